// Round 6
// baseline (246.426 us; speedup 1.0000x reference)
//
#include <hip/hip_runtime.h>
#include <hip/hip_bf16.h>
#include <stdint.h>

typedef short bf16x8 __attribute__((ext_vector_type(8)));
typedef float f32x4  __attribute__((ext_vector_type(4)));
typedef float f32x16 __attribute__((ext_vector_type(16)));
typedef unsigned int u32;

#define N_SP 4096
// 8^-0.5 * log2(e): fold softmax scale + exp->exp2 conversion into Q
#define QSCALE 0.5100697284f

__device__ inline unsigned short f2bf(float f) {
    unsigned u = __float_as_uint(f);
    u += 0x7fff + ((u >> 16) & 1);
    return (unsigned short)(u >> 16);
}
__device__ inline u32 cvtpk_bf16(float lo, float hi) {
    u32 r;
    asm("v_cvt_pk_bf16_f32 %0, %1, %2" : "=v"(r) : "v"(lo), "v"(hi));
    return r;
}
__device__ inline void pl32swap(u32& a, u32& b) {
    asm volatile("v_permlane32_swap_b32 %0, %1" : "+v"(a), "+v"(b));
}

union U { u32 w[4]; bf16x8 v; };

// Workspace layouts (bf16), per br (br = b*2 + branch):
//  Q: [qt][l*8+j] -> B-frag lane l: Q[d=(l>>5)*8+j][q=l&31]
//  K: [nt][l*8+j] -> A-frag lane l: K[key=l&31][d=(l>>5)*8+j]
//  V: [nt][(kt*2+ct)*512 + l*8 + j] -> B-frag lane l: V[key=kt*16+(l>>5)*8+j][c=ct*32+(l&31)]

// ---------------- Stage 1: dual-branch QKV projection, all stores coalesced ---------
// 512 blocks = 4 b x 128 ntile (32 n each); 512 thr = 8 waves:
//   og0: Q both branches (16 shared dots, bias folded, permuted stores)
//   og1: K br(h) via x(h)
//   og2-7: V (12 half-wave roles x ~11 channels) -> LDS f32 tile -> vector store-out
__global__ __launch_bounds__(512, 4) void stage1_kernel(
    const float* __restrict__ in1, const float* __restrict__ in2,
    const float* __restrict__ wq1, const float* __restrict__ bq1,
    const float* __restrict__ wq2, const float* __restrict__ bq2,
    const float* __restrict__ wq3, const float* __restrict__ bq3,
    const float* __restrict__ wq4, const float* __restrict__ bq4,
    const float* __restrict__ wk,  const float* __restrict__ bk,
    const float* __restrict__ wv,  const float* __restrict__ bv,
    const float* __restrict__ wk2, const float* __restrict__ bk2,
    const float* __restrict__ wv2, const float* __restrict__ bv2,
    unsigned short* __restrict__ Qs, unsigned short* __restrict__ Ks,
    unsigned short* __restrict__ Vs)
{
    __shared__ float vt[2][64][34];   // V f32 staging [branch][c][n(+pad)]

    const int bid = blockIdx.x;
    const int b = bid & 3;
    const int ntl = bid >> 2;          // 0..127
    const int tid = threadIdx.x;
    const int og = tid >> 6;           // wave role
    const int l = tid & 63;
    const int h = l >> 5;              // half-wave
    const int nl = l & 31;
    const int n = ntl * 32 + nl;

    const float* x1p = in1 + (size_t)b * 64 * N_SP + n;
    const float* x2p = in2 + (size_t)b * 64 * N_SP + n;

    if (og == 0) {
        // Q. dots: h0 -> A=q1*x1 (d0-3), B=q3*M3 (d4-7); h1 -> C=q4*M4, D=q2*x2
        // br0 = [A,B,C,D] d0..15 ; br1 = [D,C,B,A]  (biases shared per dot group)
        const float* wA = h ? wq4 : wq1;  const float* wB = h ? wq2 : wq3;
        const float* bA = h ? bq4 : bq1;  const float* bB = h ? bq2 : bq3;
        const float c1A = h ? (1.f/3.f) : 1.f,       c2A = h ? (2.f/3.f) : 0.f;
        const float c1B = h ? 0.f       : (2.f/3.f), c2B = h ? 1.f       : (1.f/3.f);
        float dot[8];
        #pragma unroll
        for (int o = 0; o < 4; o++) { dot[o] = bA[o]; dot[4 + o] = bB[o]; }
        #pragma unroll
        for (int g = 0; g < 8; g++) {
            float mA[8], mB[8];
            #pragma unroll
            for (int cc = 0; cc < 8; cc++) {
                float x1 = x1p[(size_t)(g * 8 + cc) * N_SP];
                float x2 = x2p[(size_t)(g * 8 + cc) * N_SP];
                mA[cc] = c1A * x1 + c2A * x2;
                mB[cc] = c1B * x1 + c2B * x2;
            }
            #pragma unroll
            for (int o = 0; o < 4; o++) {
                const f32x4* wa = (const f32x4*)&wA[o * 64 + g * 8];
                const f32x4* wb = (const f32x4*)&wB[o * 64 + g * 8];
                f32x4 a0 = wa[0], a1 = wa[1], b0 = wb[0], b1 = wb[1];
                #pragma unroll
                for (int cc = 0; cc < 4; cc++) {
                    dot[o]     += a0[cc] * mA[cc] + a1[cc] * mA[4 + cc];
                    dot[4 + o] += b0[cc] * mB[cc] + b1[cc] * mB[4 + cc];
                }
            }
        }
        bf16x8 v0, v1;
        #pragma unroll
        for (int j = 0; j < 8; j++) {
            v0[j] = (short)f2bf(dot[j] * QSCALE);
            v1[j] = (short)f2bf(dot[(j + 4) & 7] * QSCALE);   // [dot4..7, dot0..3]
        }
        *(bf16x8*)(Qs + (size_t)(b * 2)     * 65536 + ntl * 512 + l * 8) = v0;
        *(bf16x8*)(Qs + (size_t)(b * 2 + 1) * 65536 + ntl * 512 + (1 - h) * 256 + nl * 8) = v1;
    } else if (og == 1) {
        // K for branch h via x(h)
        const float* wkb = h ? wk2 : wk;  const float* bkb = h ? bk2 : bk;
        const float* xp = h ? x2p : x1p;
        float dot[16];
        #pragma unroll
        for (int o = 0; o < 16; o++) dot[o] = bkb[o];
        #pragma unroll
        for (int g = 0; g < 8; g++) {
            float xc[8];
            #pragma unroll
            for (int cc = 0; cc < 8; cc++) xc[cc] = xp[(size_t)(g * 8 + cc) * N_SP];
            #pragma unroll
            for (int o = 0; o < 16; o++) {
                const f32x4* wp = (const f32x4*)&wkb[o * 64 + g * 8];
                f32x4 w0 = wp[0], w1 = wp[1];
                #pragma unroll
                for (int cc = 0; cc < 4; cc++)
                    dot[o] += w0[cc] * xc[cc] + w1[cc] * xc[4 + cc];
            }
        }
        unsigned short* kb0 = Ks + (size_t)(b * 2 + h) * 65536 + ntl * 512 + nl * 8;
        bf16x8 kv0, kv1;
        #pragma unroll
        for (int j = 0; j < 8; j++) { kv0[j] = (short)f2bf(dot[j]); kv1[j] = (short)f2bf(dot[8 + j]); }
        *(bf16x8*)(kb0) = kv0;
        *(bf16x8*)(kb0 + 256) = kv1;
    } else {
        // V half-wave roles: vr 0..11 -> (branch, c0) with 11 channels (tail overlap ok)
        const int vr = (og - 2) * 2 + h;
        const int br2 = (vr >= 6) ? 1 : 0;
        const int idx = vr - 6 * br2;
        const int c0 = (idx == 5) ? 53 : idx * 11;
        const float* wvb = br2 ? wv2 : wv;  const float* bvb = br2 ? bv2 : bv;
        const float* xp = br2 ? x2p : x1p;
        float dot[11];
        #pragma unroll
        for (int o = 0; o < 11; o++) dot[o] = bvb[c0 + o];
        #pragma unroll
        for (int g = 0; g < 8; g++) {
            float xc[8];
            #pragma unroll
            for (int cc = 0; cc < 8; cc++) xc[cc] = xp[(size_t)(g * 8 + cc) * N_SP];
            #pragma unroll
            for (int o = 0; o < 11; o++) {
                const f32x4* wp = (const f32x4*)&wvb[(c0 + o) * 64 + g * 8];
                f32x4 w0 = wp[0], w1 = wp[1];
                #pragma unroll
                for (int cc = 0; cc < 4; cc++)
                    dot[o] += w0[cc] * xc[cc] + w1[cc] * xc[4 + cc];
            }
        }
        #pragma unroll
        for (int o = 0; o < 11; o++) vt[br2][c0 + o][nl] = dot[o];
    }
    __syncthreads();

    // V store-out: 512 chunks (2 br x 256), one bf16x8 per thread, fully coalesced
    {
        const int br2s = tid >> 8;
        const int ci = tid & 255;
        const int c = ((ci >> 6) & 1) * 32 + (ci & 31);
        const int k0 = (ci >> 7) * 16 + ((ci >> 5) & 1) * 8;
        const float* row = &vt[br2s][c][k0];
        bf16x8 ov;
        #pragma unroll
        for (int j = 0; j < 8; j++) ov[j] = (short)f2bf(row[j]);
        *(bf16x8*)(Vs + (size_t)(b * 2 + br2s) * 262144 + (size_t)ntl * 2048 +
                   (size_t)ci * 8) = ov;
    }
}

// ---------------- Stage 2: q-QUAD waves, key-split 8, in-register softmax ------------
#define SOFTPV(QT, ACCA, ACCB) do {                                               \
    f32x16 s_ = __builtin_amdgcn_mfma_f32_32x32x16_bf16(kfA, aq##QT, z16, 0, 0, 0); \
    float p_[16];                                                                 \
    _Pragma("unroll")                                                             \
    for (int r_ = 0; r_ < 16; ++r_) p_[r_] = __builtin_amdgcn_exp2f(s_[r_]);      \
    rsum##QT += (((p_[0]+p_[1])+(p_[2]+p_[3]))+((p_[4]+p_[5])+(p_[6]+p_[7])))     \
              + (((p_[8]+p_[9])+(p_[10]+p_[11]))+((p_[12]+p_[13])+(p_[14]+p_[15]))); \
    u32 a0 = cvtpk_bf16(p_[0], p_[1]),  a2 = cvtpk_bf16(p_[4], p_[5]);            \
    pl32swap(a0, a2);                                                             \
    u32 a1 = cvtpk_bf16(p_[2], p_[3]),  a3 = cvtpk_bf16(p_[6], p_[7]);            \
    pl32swap(a1, a3);                                                             \
    u32 c0 = cvtpk_bf16(p_[8], p_[9]),  c2 = cvtpk_bf16(p_[12], p_[13]);          \
    pl32swap(c0, c2);                                                             \
    u32 c1 = cvtpk_bf16(p_[10], p_[11]), c3 = cvtpk_bf16(p_[14], p_[15]);         \
    pl32swap(c1, c3);                                                             \
    U u0_, u1_;                                                                   \
    u0_.w[0]=a0; u0_.w[1]=a1; u0_.w[2]=a2; u0_.w[3]=a3;                           \
    u1_.w[0]=c0; u1_.w[1]=c1; u1_.w[2]=c2; u1_.w[3]=c3;                           \
    ACCA = __builtin_amdgcn_mfma_f32_32x32x16_bf16(u0_.v, vf0, ACCA, 0, 0, 0);    \
    ACCB = __builtin_amdgcn_mfma_f32_32x32x16_bf16(u0_.v, vf1, ACCB, 0, 0, 0);    \
    ACCA = __builtin_amdgcn_mfma_f32_32x32x16_bf16(u1_.v, vf2, ACCA, 0, 0, 0);    \
    ACCB = __builtin_amdgcn_mfma_f32_32x32x16_bf16(u1_.v, vf3, ACCB, 0, 0, 0);    \
} while (0)

#define EPI(QT, ACCA, ACCB) do {                                                  \
    float rs_ = rsum##QT + __shfl_xor(rsum##QT, 32, 64);                          \
    if (l < 32) rsl[w][l] = rs_;                                                  \
    _Pragma("unroll")                                                             \
    for (int r_ = 0; r_ < 16; ++r_) {                                             \
        int qrow_ = (r_ & 3) + 8 * (r_ >> 2) + 4 * hi;                            \
        accb[w][q31][qrow_]      = ACCA[r_];                                      \
        accb[w][32 + q31][qrow_] = ACCB[r_];                                      \
    }                                                                             \
    __syncthreads();                                                              \
    if (tid < 32) invl[tid] = 1.0f /                                              \
        (((rsl[0][tid]+rsl[1][tid])+(rsl[2][tid]+rsl[3][tid])) +                  \
         ((rsl[4][tid]+rsl[5][tid])+(rsl[6][tid]+rsl[7][tid])));                  \
    __syncthreads();                                                              \
    {                                                                             \
        const int c_ = tid >> 3, mg_ = tid & 7;                                   \
        const int m_ = qq * 128 + (QT) * 32 + mg_ * 4;                            \
        f32x4 o_;                                                                 \
        _Pragma("unroll")                                                         \
        for (int mi_ = 0; mi_ < 4; ++mi_) {                                       \
            int q_ = mg_ * 4 + mi_;                                               \
            float v_ = ((accb[0][c_][q_]+accb[1][c_][q_])+(accb[2][c_][q_]+accb[3][c_][q_])) \
                     + ((accb[4][c_][q_]+accb[5][c_][q_])+(accb[6][c_][q_]+accb[7][c_][q_])); \
            o_[mi_] = g * (v_ * invl[q_]) + featp[(size_t)c_ * N_SP + m_ + mi_];  \
        }                                                                         \
        *(f32x4*)(outp + (size_t)c_ * N_SP + m_) = o_;                            \
    }                                                                             \
    __syncthreads();                                                              \
} while (0)

__global__ __launch_bounds__(512, 2) void attn_kernel(
    const unsigned short* __restrict__ Qs, const unsigned short* __restrict__ Ks,
    const unsigned short* __restrict__ Vs,
    const float* __restrict__ in1, const float* __restrict__ in2,
    const float* __restrict__ gamma_p, float* __restrict__ out)
{
    __shared__ float accb[8][64][33];   // [ksplit][c][q], reused per qt round
    __shared__ float rsl[8][32];
    __shared__ float invl[32];

    const int bid = blockIdx.x;        // 256 blocks = 8 br x 32 quads
    const int br = bid & 7;            // XCD affinity
    const int qq = bid >> 3;           // quad index 0..31 (128 q-rows)
    const int b = br >> 1, rr = br & 1;
    const int tid = threadIdx.x;
    const int w = tid >> 6;            // wave = key-split 0..7 (512 keys each)
    const int l = tid & 63;
    const int q31 = l & 31, hi = l >> 5;

    const unsigned short* Qb = Qs + (size_t)br * 65536;
    const unsigned short* Kb = Ks + (size_t)br * 65536;
    const unsigned short* Vb = Vs + (size_t)br * 262144;

    // 4 Q B-fragments (q-tiles qq*4 .. +3), held for the whole kernel
    const bf16x8 aq0 = *(const bf16x8*)(Qb + (size_t)(qq * 4 + 0) * 512 + l * 8);
    const bf16x8 aq1 = *(const bf16x8*)(Qb + (size_t)(qq * 4 + 1) * 512 + l * 8);
    const bf16x8 aq2 = *(const bf16x8*)(Qb + (size_t)(qq * 4 + 2) * 512 + l * 8);
    const bf16x8 aq3 = *(const bf16x8*)(Qb + (size_t)(qq * 4 + 3) * 512 + l * 8);

    const f32x16 z16 = {0,0,0,0,0,0,0,0,0,0,0,0,0,0,0,0};
    f32x16 acc00 = z16, acc01 = z16;   // qt0: c0..31 / c32..63
    f32x16 acc10 = z16, acc11 = z16;
    f32x16 acc20 = z16, acc21 = z16;
    f32x16 acc30 = z16, acc31 = z16;
    float rsum0 = 0.f, rsum1 = 0.f, rsum2 = 0.f, rsum3 = 0.f;

    const unsigned short* kbase = Kb + (size_t)(w * 16) * 512 + l * 8;
    const unsigned short* vbase = Vb + (size_t)(w * 16) * 2048 + l * 8;

    bf16x8 kfA = *(const bf16x8*)kbase;
    #pragma unroll 1
    for (int t = 0; t < 16; ++t) {
        // V for current tile: latency covered by QK MFMAs + softmax below
        bf16x8 vf0 = *(const bf16x8*)(vbase);
        bf16x8 vf1 = *(const bf16x8*)(vbase + 512);
        bf16x8 vf2 = *(const bf16x8*)(vbase + 1024);
        bf16x8 vf3 = *(const bf16x8*)(vbase + 1536);
        // K prefetch one tile ahead (last read lands in adjacent ws region; unused)
        bf16x8 kfN = *(const bf16x8*)(kbase + 512);

        SOFTPV(0, acc00, acc01);
        SOFTPV(1, acc10, acc11);
        SOFTPV(2, acc20, acc21);
        SOFTPV(3, acc30, acc31);

        kfA = kfN;
        kbase += 512;
        vbase += 2048;
    }

    const float g = gamma_p[0];
    const float* featp = (rr ? in2 : in1) + (size_t)b * 64 * N_SP;
    float* outp = out + (size_t)rr * (4ull * 64 * N_SP) + (size_t)b * 64 * N_SP;

    EPI(0, acc00, acc01);
    EPI(1, acc10, acc11);
    EPI(2, acc20, acc21);
    EPI(3, acc30, acc31);
}

extern "C" void kernel_launch(void* const* d_in, const int* in_sizes, int n_in,
                              void* d_out, int out_size, void* d_ws, size_t ws_size,
                              hipStream_t stream) {
    const float* in1 = (const float*)d_in[0];
    const float* in2 = (const float*)d_in[1];
    const float* wq1 = (const float*)d_in[2];  const float* bq1 = (const float*)d_in[3];
    const float* wq2 = (const float*)d_in[4];  const float* bq2 = (const float*)d_in[5];
    const float* wq3 = (const float*)d_in[6];  const float* bq3 = (const float*)d_in[7];
    const float* wq4 = (const float*)d_in[8];  const float* bq4 = (const float*)d_in[9];
    const float* wk  = (const float*)d_in[10]; const float* bk  = (const float*)d_in[11];
    const float* wv  = (const float*)d_in[12]; const float* bv  = (const float*)d_in[13];
    const float* wk2 = (const float*)d_in[14]; const float* bk2 = (const float*)d_in[15];
    const float* wv2 = (const float*)d_in[16]; const float* bv2 = (const float*)d_in[17];
    const float* gamma_p = (const float*)d_in[18];

    unsigned short* Qs = (unsigned short*)d_ws;          // 8 * 65536 shorts
    unsigned short* Ks = Qs + (size_t)8 * 65536;         // 8 * 65536 shorts
    unsigned short* Vs = Ks + (size_t)8 * 65536;         // 8 * 262144 shorts

    stage1_kernel<<<dim3(512), 512, 0, stream>>>(in1, in2, wq1, bq1, wq2, bq2,
                                                 wq3, bq3, wq4, bq4, wk, bk, wv, bv,
                                                 wk2, bk2, wv2, bv2, Qs, Ks, Vs);
    attn_kernel<<<dim3(256), 512, 0, stream>>>(Qs, Ks, Vs, in1, in2, gamma_p,
                                               (float*)d_out);
}

// Round 8
// 140.385 us; speedup vs baseline: 1.7554x; 1.7554x over previous
//
#include <hip/hip_runtime.h>
#include <hip/hip_bf16.h>
#include <stdint.h>

typedef short bf16x8 __attribute__((ext_vector_type(8)));
typedef float f32x4  __attribute__((ext_vector_type(4)));
typedef float f32x16 __attribute__((ext_vector_type(16)));
typedef unsigned int u32;

#define N_SP 4096
// 8^-0.5 * log2(e): fold softmax scale + exp->exp2 conversion into Q
#define QSCALE 0.5100697284f

__device__ inline unsigned short f2bf(float f) {
    unsigned u = __float_as_uint(f);
    u += 0x7fff + ((u >> 16) & 1);
    return (unsigned short)(u >> 16);
}
__device__ inline float bf2f(short s) {
    return __uint_as_float(((unsigned)(unsigned short)s) << 16);
}
__device__ inline u32 cvtpk_bf16(float lo, float hi) {
    u32 r;
    asm("v_cvt_pk_bf16_f32 %0, %1, %2" : "=v"(r) : "v"(lo), "v"(hi));
    return r;
}
__device__ inline void pl32swap(u32& a, u32& b) {
    asm volatile("v_permlane32_swap_b32 %0, %1" : "+v"(a), "+v"(b));
}

union U { u32 w[4]; bf16x8 v; };

// Workspace layouts (bf16), per br (br = b*2 + branch):
//  Q: [qt][l*8+j] -> B-frag lane l: Q[d=(l>>5)*8+j][q=l&31]
//  K: [nt][l*8+j] -> A-frag lane l: K[key=l&31][d=(l>>5)*8+j]
//  V: [nt][(kt*2+ct)*512 + hi*256 + c31*8 + j] = V[key=kt*16+hi*8+j][c=ct*32+c31]
//      -> B-frag lane l loads b128 at nt*2048 + (kt*2+ct)*512 + l*8

// ---------------- Stage 1: QKV projection (R3 structure + coalesced V store) --------
// grid 1024 = 8 br x 128 ntile (32 n each); 256 thr, half-wave output roles.
__global__ __launch_bounds__(256, 4) void stage1_kernel(
    const float* __restrict__ in1, const float* __restrict__ in2,
    const float* __restrict__ wq1, const float* __restrict__ bq1,
    const float* __restrict__ wq2, const float* __restrict__ bq2,
    const float* __restrict__ wq3, const float* __restrict__ bq3,
    const float* __restrict__ wq4, const float* __restrict__ bq4,
    const float* __restrict__ wk,  const float* __restrict__ bk,
    const float* __restrict__ wv,  const float* __restrict__ bv,
    const float* __restrict__ wk2, const float* __restrict__ bk2,
    const float* __restrict__ wv2, const float* __restrict__ bv2,
    unsigned short* __restrict__ Qs, unsigned short* __restrict__ Ks,
    unsigned short* __restrict__ Vs)
{
    __shared__ unsigned short w1h[16][64];   // effective q weight on input1 (scaled)
    __shared__ unsigned short w2h[16][64];   // effective q weight on input2 (scaled)
    __shared__ unsigned short wkh[16][64];
    __shared__ unsigned short wvh[64][64];
    __shared__ unsigned short vth[64][40];   // V bf16 staging [c][key] (stride 40)
    __shared__ float qb[16], kbb[16], vbb[64];

    const int bid = blockIdx.x;
    const int br = bid & 7;          // XCD affinity (same mapping as attn)
    const int ntl = bid >> 3;        // 0..127
    const int b = br >> 1, rr = br & 1;
    const int tid = threadIdx.x;

    // q_in1 = [q1, q3, q4, q2]; q_in2 = [q2, q4, q3, q1]
    // i3 = (2/3)i1 + (1/3)i2 ; i4 = (1/3)i1 + (2/3)i2
    const float* wqs[4]; const float* bqs[4]; float c1s[4], c2s[4];
    if (rr == 0) {
        wqs[0]=wq1; bqs[0]=bq1; c1s[0]=1.f;       c2s[0]=0.f;
        wqs[1]=wq3; bqs[1]=bq3; c1s[1]=2.f/3.f;   c2s[1]=1.f/3.f;
        wqs[2]=wq4; bqs[2]=bq4; c1s[2]=1.f/3.f;   c2s[2]=2.f/3.f;
        wqs[3]=wq2; bqs[3]=bq2; c1s[3]=0.f;       c2s[3]=1.f;
    } else {
        wqs[0]=wq2; bqs[0]=bq2; c1s[0]=0.f;       c2s[0]=1.f;
        wqs[1]=wq4; bqs[1]=bq4; c1s[1]=1.f/3.f;   c2s[1]=2.f/3.f;
        wqs[2]=wq3; bqs[2]=bq3; c1s[2]=2.f/3.f;   c2s[2]=1.f/3.f;
        wqs[3]=wq1; bqs[3]=bq1; c1s[3]=1.f;       c2s[3]=0.f;
    }
    const float* wkp = rr ? wk2 : wk;  const float* bkp = rr ? bk2 : bk;
    const float* wvp = rr ? wv2 : wv;  const float* bvp = rr ? bv2 : bv;

    for (int e = tid; e < 1024; e += 256) {
        int g = e >> 8;
        int h = e >> 6;
        int ch = e & 63;
        float wq_ = wqs[g][e & 255];
        w1h[h][ch] = f2bf(c1s[g] * wq_ * QSCALE);
        w2h[h][ch] = f2bf(c2s[g] * wq_ * QSCALE);
        wkh[h][ch] = f2bf(wkp[e]);
    }
    for (int e = tid; e < 4096; e += 256) wvh[e >> 6][e & 63] = f2bf(wvp[e]);
    if (tid < 16) { qb[tid] = bqs[tid >> 2][tid & 3] * QSCALE; kbb[tid] = bkp[tid]; }
    if (tid < 64) vbb[tid] = bvp[tid];
    __syncthreads();

    const int nl = tid & 31;         // n within tile (= key/q index)
    const int og = tid >> 5;         // half-wave output role 0..7
    const int n = ntl * 32 + nl;
    const float* x1p = in1 + (size_t)b * 64 * N_SP + n;
    const float* x2p = in2 + (size_t)b * 64 * N_SP + n;
    const float* xfp = rr ? x2p : x1p;

    if (og < 2) {
        // Q channels d = og*8 .. +7 (needs both inputs)
        float acc[8];
        #pragma unroll
        for (int o = 0; o < 8; o++) acc[o] = qb[og * 8 + o];
        for (int g = 0; g < 8; g++) {
            float x1v[8], x2v[8];
            #pragma unroll
            for (int cc = 0; cc < 8; cc++) {
                x1v[cc] = x1p[(size_t)(g * 8 + cc) * N_SP];
                x2v[cc] = x2p[(size_t)(g * 8 + cc) * N_SP];
            }
            #pragma unroll
            for (int o = 0; o < 8; o++) {
                bf16x8 w1v = *(const bf16x8*)(&w1h[og * 8 + o][g * 8]);
                bf16x8 w2v = *(const bf16x8*)(&w2h[og * 8 + o][g * 8]);
                #pragma unroll
                for (int cc = 0; cc < 8; cc++)
                    acc[o] += bf2f(w1v[cc]) * x1v[cc] + bf2f(w2v[cc]) * x2v[cc];
            }
        }
        bf16x8 qv;
        #pragma unroll
        for (int o = 0; o < 8; o++) qv[o] = (short)f2bf(acc[o]);
        *(bf16x8*)(Qs + (size_t)br * 65536 + ntl * 512 + og * 256 + nl * 8) = qv;
    } else if (og < 4) {
        // K channels d = dg*8 .. +7
        const int dg = og - 2;
        float acc[8];
        #pragma unroll
        for (int o = 0; o < 8; o++) acc[o] = kbb[dg * 8 + o];
        for (int g = 0; g < 8; g++) {
            float xfv[8];
            #pragma unroll
            for (int cc = 0; cc < 8; cc++) xfv[cc] = xfp[(size_t)(g * 8 + cc) * N_SP];
            #pragma unroll
            for (int o = 0; o < 8; o++) {
                bf16x8 wkv = *(const bf16x8*)(&wkh[dg * 8 + o][g * 8]);
                #pragma unroll
                for (int cc = 0; cc < 8; cc++)
                    acc[o] += bf2f(wkv[cc]) * xfv[cc];
            }
        }
        bf16x8 kv;
        #pragma unroll
        for (int o = 0; o < 8; o++) kv[o] = (short)f2bf(acc[o]);
        *(bf16x8*)(Ks + (size_t)br * 65536 + ntl * 512 + dg * 256 + nl * 8) = kv;
    } else {
        // V channels c = cg*16 .. +15 -> LDS staging (coalesced store-out below)
        const int cg = og - 4;
        float acc[16];
        #pragma unroll
        for (int j = 0; j < 16; j++) acc[j] = vbb[cg * 16 + j];
        for (int g = 0; g < 8; g++) {
            float xfv[8];
            #pragma unroll
            for (int cc = 0; cc < 8; cc++) xfv[cc] = xfp[(size_t)(g * 8 + cc) * N_SP];
            #pragma unroll
            for (int j = 0; j < 16; j++) {
                bf16x8 wvv = *(const bf16x8*)(&wvh[cg * 16 + j][g * 8]);
                #pragma unroll
                for (int cc = 0; cc < 8; cc++)
                    acc[j] += bf2f(wvv[cc]) * xfv[cc];
            }
        }
        #pragma unroll
        for (int j = 0; j < 16; j++) vth[cg * 16 + j][nl] = f2bf(acc[j]);
    }
    __syncthreads();

    // V store-out: 256 chunks, one bf16x8 per thread, fully coalesced.
    // chunk ci: kt=ci>>7, ct=(ci>>6)&1, hi=(ci>>5)&1, c31=ci&31
    {
        const int ci = tid;
        const int c = ((ci >> 6) & 1) * 32 + (ci & 31);
        const int k0 = (ci >> 7) * 16 + ((ci >> 5) & 1) * 8;
        bf16x8 ov = *(const bf16x8*)(&vth[c][k0]);
        *(bf16x8*)(Vs + (size_t)br * 262144 + (size_t)ntl * 2048 + (size_t)ci * 8) = ov;
    }
}

// ---------------- Stage 2: q-QUAD waves, key-split 8, in-register softmax ------------
#define SOFTPV(QT, ACCA, ACCB) do {                                               \
    f32x16 s_ = __builtin_amdgcn_mfma_f32_32x32x16_bf16(kfA, aq##QT, z16, 0, 0, 0); \
    float p_[16];                                                                 \
    _Pragma("unroll")                                                             \
    for (int r_ = 0; r_ < 16; ++r_) p_[r_] = __builtin_amdgcn_exp2f(s_[r_]);      \
    rsum##QT += (((p_[0]+p_[1])+(p_[2]+p_[3]))+((p_[4]+p_[5])+(p_[6]+p_[7])))     \
              + (((p_[8]+p_[9])+(p_[10]+p_[11]))+((p_[12]+p_[13])+(p_[14]+p_[15]))); \
    u32 a0 = cvtpk_bf16(p_[0], p_[1]),  a2 = cvtpk_bf16(p_[4], p_[5]);            \
    pl32swap(a0, a2);                                                             \
    u32 a1 = cvtpk_bf16(p_[2], p_[3]),  a3 = cvtpk_bf16(p_[6], p_[7]);            \
    pl32swap(a1, a3);                                                             \
    u32 c0 = cvtpk_bf16(p_[8], p_[9]),  c2 = cvtpk_bf16(p_[12], p_[13]);          \
    pl32swap(c0, c2);                                                             \
    u32 c1 = cvtpk_bf16(p_[10], p_[11]), c3 = cvtpk_bf16(p_[14], p_[15]);         \
    pl32swap(c1, c3);                                                             \
    U u0_, u1_;                                                                   \
    u0_.w[0]=a0; u0_.w[1]=a1; u0_.w[2]=a2; u0_.w[3]=a3;                           \
    u1_.w[0]=c0; u1_.w[1]=c1; u1_.w[2]=c2; u1_.w[3]=c3;                           \
    ACCA = __builtin_amdgcn_mfma_f32_32x32x16_bf16(u0_.v, vA0, ACCA, 0, 0, 0);    \
    ACCB = __builtin_amdgcn_mfma_f32_32x32x16_bf16(u0_.v, vA1, ACCB, 0, 0, 0);    \
    ACCA = __builtin_amdgcn_mfma_f32_32x32x16_bf16(u1_.v, vA2, ACCA, 0, 0, 0);    \
    ACCB = __builtin_amdgcn_mfma_f32_32x32x16_bf16(u1_.v, vA3, ACCB, 0, 0, 0);    \
} while (0)

#define EPI(QT, ACCA, ACCB) do {                                                  \
    float rs_ = rsum##QT + __shfl_xor(rsum##QT, 32, 64);                          \
    if (l < 32) rsl[w][l] = rs_;                                                  \
    _Pragma("unroll")                                                             \
    for (int r_ = 0; r_ < 16; ++r_) {                                             \
        int qrow_ = (r_ & 3) + 8 * (r_ >> 2) + 4 * hi;                            \
        accb[w][q31][qrow_]      = ACCA[r_];                                      \
        accb[w][32 + q31][qrow_] = ACCB[r_];                                      \
    }                                                                             \
    __syncthreads();                                                              \
    if (tid < 32) invl[tid] = 1.0f /                                              \
        (((rsl[0][tid]+rsl[1][tid])+(rsl[2][tid]+rsl[3][tid])) +                  \
         ((rsl[4][tid]+rsl[5][tid])+(rsl[6][tid]+rsl[7][tid])));                  \
    __syncthreads();                                                              \
    {                                                                             \
        const int c_ = tid >> 3, mg_ = tid & 7;                                   \
        const int m_ = qq * 128 + (QT) * 32 + mg_ * 4;                            \
        f32x4 o_;                                                                 \
        _Pragma("unroll")                                                         \
        for (int mi_ = 0; mi_ < 4; ++mi_) {                                       \
            int q_ = mg_ * 4 + mi_;                                               \
            float v_ = ((accb[0][c_][q_]+accb[1][c_][q_])+(accb[2][c_][q_]+accb[3][c_][q_])) \
                     + ((accb[4][c_][q_]+accb[5][c_][q_])+(accb[6][c_][q_]+accb[7][c_][q_])); \
            o_[mi_] = g * (v_ * invl[q_]) + featp[(size_t)c_ * N_SP + m_ + mi_];  \
        }                                                                         \
        *(f32x4*)(outp + (size_t)c_ * N_SP + m_) = o_;                            \
    }                                                                             \
    __syncthreads();                                                              \
} while (0)

__global__ __launch_bounds__(512, 2) void attn_kernel(
    const unsigned short* __restrict__ Qs, const unsigned short* __restrict__ Ks,
    const unsigned short* __restrict__ Vs,
    const float* __restrict__ in1, const float* __restrict__ in2,
    const float* __restrict__ gamma_p, float* __restrict__ out)
{
    __shared__ float accb[8][64][33];   // [ksplit][c][q], reused per qt round
    __shared__ float rsl[8][32];
    __shared__ float invl[32];

    const int bid = blockIdx.x;        // 256 blocks = 8 br x 32 quads
    const int br = bid & 7;            // XCD affinity
    const int qq = bid >> 3;           // quad index 0..31 (128 q-rows)
    const int b = br >> 1, rr = br & 1;
    const int tid = threadIdx.x;
    const int w = tid >> 6;            // wave = key-split 0..7 (512 keys each)
    const int l = tid & 63;
    const int q31 = l & 31, hi = l >> 5;

    const unsigned short* Qb = Qs + (size_t)br * 65536;
    const unsigned short* Kb = Ks + (size_t)br * 65536;
    const unsigned short* Vb = Vs + (size_t)br * 262144;

    // 4 Q B-fragments (q-tiles qq*4 .. +3), held for the whole kernel
    const bf16x8 aq0 = *(const bf16x8*)(Qb + (size_t)(qq * 4 + 0) * 512 + l * 8);
    const bf16x8 aq1 = *(const bf16x8*)(Qb + (size_t)(qq * 4 + 1) * 512 + l * 8);
    const bf16x8 aq2 = *(const bf16x8*)(Qb + (size_t)(qq * 4 + 2) * 512 + l * 8);
    const bf16x8 aq3 = *(const bf16x8*)(Qb + (size_t)(qq * 4 + 3) * 512 + l * 8);

    const f32x16 z16 = {0,0,0,0,0,0,0,0,0,0,0,0,0,0,0,0};
    f32x16 acc00 = z16, acc01 = z16;   // qt0: c0..31 / c32..63
    f32x16 acc10 = z16, acc11 = z16;
    f32x16 acc20 = z16, acc21 = z16;
    f32x16 acc30 = z16, acc31 = z16;
    float rsum0 = 0.f, rsum1 = 0.f, rsum2 = 0.f, rsum3 = 0.f;

    const unsigned short* kbase = Kb + (size_t)(w * 16) * 512 + l * 8;
    const unsigned short* vbase = Vb + (size_t)(w * 16) * 2048 + l * 8;

    // double-buffered register prefetch: K and V one tile ahead
    bf16x8 kfA = *(const bf16x8*)kbase;
    bf16x8 vA0 = *(const bf16x8*)(vbase);
    bf16x8 vA1 = *(const bf16x8*)(vbase + 512);
    bf16x8 vA2 = *(const bf16x8*)(vbase + 1024);
    bf16x8 vA3 = *(const bf16x8*)(vbase + 1536);

    #pragma unroll 1
    for (int t = 0; t < 16; ++t) {
        const int nx = (t < 15) ? 1 : 0;   // clamp: last iter re-reads own tile
        bf16x8 kfB = *(const bf16x8*)(kbase + nx * 512);
        bf16x8 vB0 = *(const bf16x8*)(vbase + nx * 2048);
        bf16x8 vB1 = *(const bf16x8*)(vbase + nx * 2048 + 512);
        bf16x8 vB2 = *(const bf16x8*)(vbase + nx * 2048 + 1024);
        bf16x8 vB3 = *(const bf16x8*)(vbase + nx * 2048 + 1536);

        SOFTPV(0, acc00, acc01);
        SOFTPV(1, acc10, acc11);
        SOFTPV(2, acc20, acc21);
        SOFTPV(3, acc30, acc31);

        kfA = kfB; vA0 = vB0; vA1 = vB1; vA2 = vB2; vA3 = vB3;
        kbase += 512;
        vbase += 2048;
    }

    const float g = gamma_p[0];
    const float* featp = (rr ? in2 : in1) + (size_t)b * 64 * N_SP;
    float* outp = out + (size_t)rr * (4ull * 64 * N_SP) + (size_t)b * 64 * N_SP;

    EPI(0, acc00, acc01);
    EPI(1, acc10, acc11);
    EPI(2, acc20, acc21);
    EPI(3, acc30, acc31);
}

extern "C" void kernel_launch(void* const* d_in, const int* in_sizes, int n_in,
                              void* d_out, int out_size, void* d_ws, size_t ws_size,
                              hipStream_t stream) {
    const float* in1 = (const float*)d_in[0];
    const float* in2 = (const float*)d_in[1];
    const float* wq1 = (const float*)d_in[2];  const float* bq1 = (const float*)d_in[3];
    const float* wq2 = (const float*)d_in[4];  const float* bq2 = (const float*)d_in[5];
    const float* wq3 = (const float*)d_in[6];  const float* bq3 = (const float*)d_in[7];
    const float* wq4 = (const float*)d_in[8];  const float* bq4 = (const float*)d_in[9];
    const float* wk  = (const float*)d_in[10]; const float* bk  = (const float*)d_in[11];
    const float* wv  = (const float*)d_in[12]; const float* bv  = (const float*)d_in[13];
    const float* wk2 = (const float*)d_in[14]; const float* bk2 = (const float*)d_in[15];
    const float* wv2 = (const float*)d_in[16]; const float* bv2 = (const float*)d_in[17];
    const float* gamma_p = (const float*)d_in[18];

    unsigned short* Qs = (unsigned short*)d_ws;          // 8 * 65536 shorts
    unsigned short* Ks = Qs + (size_t)8 * 65536;         // 8 * 65536 shorts
    unsigned short* Vs = Ks + (size_t)8 * 65536;         // 8 * 262144 shorts

    stage1_kernel<<<dim3(1024), 256, 0, stream>>>(in1, in2, wq1, bq1, wq2, bq2,
                                                  wq3, bq3, wq4, bq4, wk, bk, wv, bv,
                                                  wk2, bk2, wv2, bv2, Qs, Ks, Vs);
    attn_kernel<<<dim3(256), 512, 0, stream>>>(Qs, Ks, Vs, in1, in2, gamma_p,
                                               (float*)d_out);
}